// Round 10
// baseline (66.133 us; speedup 1.0000x reference)
//
#include <hip/hip_runtime.h>

typedef short bf16x4 __attribute__((ext_vector_type(4)));
typedef short bf16x8 __attribute__((ext_vector_type(8)));
typedef float f32x4 __attribute__((ext_vector_type(4)));
typedef unsigned short u16x4 __attribute__((ext_vector_type(4)));
typedef unsigned short u16x8 __attribute__((ext_vector_type(8)));

__device__ __forceinline__ unsigned short f2bf(float f) {
  union { float f; unsigned u; } v; v.f = f;
  unsigned r = v.u + 0x7FFFu + ((v.u >> 16) & 1u);
  return (unsigned short)(r >> 16);
}
__device__ __forceinline__ unsigned fbits(float f) {
  union { float f; unsigned u; } x; x.f = f; return x.u;
}
__device__ __forceinline__ float bfloat(unsigned u) {
  union { unsigned u; float f; } x; x.u = u; return x.f;
}
__device__ __forceinline__ float fexp2(float x) {
#if __has_builtin(__builtin_amdgcn_exp2f)
  return __builtin_amdgcn_exp2f(x);
#else
  return exp2f(x);
#endif
}
// RNE packed f32->2xbf16 (verified on gfx950)
__device__ __forceinline__ unsigned cvt_pk_bf16(float a, float b) {
  unsigned r;
  asm("v_cvt_pk_bf16_f32 %0, %1, %2" : "=v"(r) : "v"(a), "v"(b));
  return r;
}
__device__ __forceinline__ f32x4 pv_mfma(bf16x4 a, bf16x4 b, f32x4 c) {
#if __has_builtin(__builtin_amdgcn_mfma_f32_16x16x16bf16_1k)
  return __builtin_amdgcn_mfma_f32_16x16x16bf16_1k(a, b, c, 0, 0, 0);
#else
  bf16x8 az = {a[0], a[1], a[2], a[3], 0, 0, 0, 0};
  bf16x8 bz = {b[0], b[1], b[2], b[3], 0, 0, 0, 0};
  return __builtin_amdgcn_mfma_f32_16x16x32_bf16(az, bz, c, 0, 0, 0);
#endif
}

// ---------- fused qkv: in-block X transpose+cast (LDS f32) + W cast + MFMA ----
__global__ __launch_bounds__(256)
void qkvT_kernel(const float* __restrict__ Xq, const float* __restrict__ Xkv,
                 const float* __restrict__ Wqkv, unsigned short* __restrict__ Y16)
{
  __shared__ float Xf[128][33];
  const int t = threadIdx.x;
  const int w = t >> 6, c = t & 15, g = (t & 63) >> 4;
  const int n0 = blockIdx.x * 32;
  const int ob = blockIdx.y;
  const float* X = (ob >= 2) ? Xkv : Xq;

  {
    const int kr = t >> 3;
    const int nc = (t & 7) * 4;
    #pragma unroll
    for (int pass = 0; pass < 4; ++pass) {
      int k = pass * 32 + kr;
      f32x4 v = *(const f32x4*)&X[k * 4096 + n0 + nc];
      Xf[k][nc + 0] = v[0];
      Xf[k][nc + 1] = v[1];
      Xf[k][nc + 2] = v[2];
      Xf[k][nc + 3] = v[3];
    }
  }

  union { unsigned u[4]; bf16x8 v; } af[4];
  {
    const float* wr = Wqkv + (ob * 64 + w * 16 + c) * 128;
    #pragma unroll
    for (int ks = 0; ks < 4; ++ks) {
      f32x4 v0 = *(const f32x4*)&wr[ks * 32 + g * 8];
      f32x4 v1 = *(const f32x4*)&wr[ks * 32 + g * 8 + 4];
      af[ks].u[0] = cvt_pk_bf16(v0[0], v0[1]);
      af[ks].u[1] = cvt_pk_bf16(v0[2], v0[3]);
      af[ks].u[2] = cvt_pk_bf16(v1[0], v1[1]);
      af[ks].u[3] = cvt_pk_bf16(v1[2], v1[3]);
    }
  }
  __syncthreads();

  union { unsigned u[4]; bf16x8 v; } bfr[2][4];
  #pragma unroll
  for (int s = 0; s < 2; ++s) {
    const int n = s * 16 + c;
    #pragma unroll
    for (int ks = 0; ks < 4; ++ks) {
      const int kb = ks * 32 + g * 8;
      #pragma unroll
      for (int m = 0; m < 4; ++m)
        bfr[s][ks].u[m] = cvt_pk_bf16(Xf[kb + 2 * m][n], Xf[kb + 2 * m + 1][n]);
    }
  }

  f32x4 acc[2] = {{0.f, 0.f, 0.f, 0.f}, {0.f, 0.f, 0.f, 0.f}};
  #pragma unroll
  for (int ks = 0; ks < 4; ++ks) {
    acc[0] = __builtin_amdgcn_mfma_f32_16x16x32_bf16(af[ks].v, bfr[0][ks].v, acc[0], 0, 0, 0);
    acc[1] = __builtin_amdgcn_mfma_f32_16x16x32_bf16(af[ks].v, bfr[1][ks].v, acc[1], 0, 0, 0);
  }
  #pragma unroll
  for (int s = 0; s < 2; ++s)
    #pragma unroll
    for (int i = 0; i < 4; ++i)
      Y16[(ob * 64 + w * 16 + 4 * g + i) * 4096 + n0 + s * 16 + c] = f2bf(acc[s][i]);
}

// ---------- depthwise 3x3 SAME, quarter-plane blocks ----------
__global__ __launch_bounds__(256)
void dwconv_kernel(const unsigned short* __restrict__ T16, const float* __restrict__ Wd,
                   const float* __restrict__ temp, unsigned short* __restrict__ Qt,
                   unsigned short* __restrict__ Kt, unsigned short* __restrict__ Vb)
{
  __shared__ float P[18 * 64];
  const int jc = blockIdx.x >> 2;
  const int qtr = blockIdx.x & 3;
  const int y0 = qtr * 16;
  const int t = threadIdx.x;
  const unsigned short* in = T16 + jc * 4096;
  #pragma unroll
  for (int i = 0; i < 5; ++i) {
    int idx = i * 256 + t;
    if (idx < 1152) {
      int row = idx >> 6, col = idx & 63;
      int sy = y0 - 1 + row;
      P[idx] = (sy >= 0 && sy < 64) ? bfloat((unsigned)in[sy * 64 + col] << 16) : 0.f;
    }
  }
  float w[9];
  #pragma unroll
  for (int k = 0; k < 9; ++k) w[k] = Wd[jc * 9 + k];
  const float scale = (jc < 128) ? temp[jc >> 5] * 1.4426950408889634f : 1.0f;
  __syncthreads();

  const int hh = (jc >> 5) & 3, dd = jc & 31;
  unsigned short* outT = (jc < 128 ? Qt : Kt) + hh * 4096 * 32 + dd;
  unsigned short* outV = Vb + (jc - 256) * 4096 + y0 * 64;
  const bool is_v = (jc >= 256);

  #pragma unroll
  for (int i = 0; i < 4; ++i) {
    int p = i * 256 + t;
    int yl = p >> 6, x = p & 63;
    float acc = 0.f;
    #pragma unroll
    for (int dy = 0; dy < 3; ++dy) {
      int base = (yl + dy) * 64 + x;
      if (x > 0)  acc += w[dy * 3 + 0] * P[base - 1];
      acc += w[dy * 3 + 1] * P[base];
      if (x < 63) acc += w[dy * 3 + 2] * P[base + 1];
    }
    unsigned short r = f2bf(acc * scale);
    if (is_v) outV[p] = r;
    else      outT[(y0 * 64 + p) * 32] = r;
  }
}

// ----------------------- flash attention (bf16 MFMA) -----------------------
// Occupancy x2: grid (128,4) = 512 blocks of 16 waves; each wave owns 32
// queries (qf[2]) x a private 256-key range -> 2 blocks/CU = 8 waves/SIMD.
// Barrier-free main loop; 3-barrier binary-tree register reduction epilogue.
__global__ __launch_bounds__(1024, 8)
void attn_kernel(const unsigned short* __restrict__ Qt,
                 const unsigned short* __restrict__ Kt,
                 const unsigned short* __restrict__ Vb,
                 unsigned short* __restrict__ Oth, unsigned short* __restrict__ Otl)
{
  __shared__ __align__(16) char lds[34944];
  float* WS  = (float*)lds;                 // 8 slots x 1024 f32 (32 KB)
  float* lf  = (float*)(lds + 32768);       // [16][32] per-wave lsum (2 KB)
  float* lfq = (float*)(lds + 34816);       // [32] final l per query
  const int t = threadIdx.x;
  const int wv = t >> 6;
  const int l = t & 63;
  const int c = l & 15, g = l >> 4;
  const int h = blockIdx.y;
  const int nq = blockIdx.x * 32;
  const int m0w = wv * 256;

  bf16x8 qf[2];
  #pragma unroll
  for (int s = 0; s < 2; ++s)
    qf[s] = *(const bf16x8*)&Qt[(h * 4096 + nq + s * 16 + c) * 32 + g * 8];

  f32x4 oh[2][2];
  #pragma unroll
  for (int s = 0; s < 2; ++s) {
    oh[s][0] = (f32x4){0.f, 0.f, 0.f, 0.f};
    oh[s][1] = (f32x4){0.f, 0.f, 0.f, 0.f};
  }
  float lsum[2] = {0.f, 0.f};

  const unsigned short* Kb  = Kt + (h * 4096 + m0w + c) * 32 + g * 8;
  const unsigned short* Vb0 = Vb + (h * 32 + c) * 4096 + m0w + g * 4;
  const unsigned short* Vb1 = Vb0 + 16 * 4096;

  #pragma unroll 4
  for (int j = 0; j < 16; ++j) {
    bf16x8 kf = *(const bf16x8*)&Kb[j * 512];
    bf16x4 vf0 = *(const bf16x4*)&Vb0[j * 16];
    bf16x4 vf1 = *(const bf16x4*)&Vb1[j * 16];
    #pragma unroll
    for (int s = 0; s < 2; ++s) {
      f32x4 z = {0.f, 0.f, 0.f, 0.f};
      f32x4 sv = __builtin_amdgcn_mfma_f32_16x16x32_bf16(kf, qf[s], z, 0, 0, 0);
      float e0 = fexp2(sv[0]);
      float e1 = fexp2(sv[1]);
      float e2 = fexp2(sv[2]);
      float e3 = fexp2(sv[3]);
      lsum[s] += (e0 + e1) + (e2 + e3);
      union { unsigned u[2]; bf16x4 v; } pu;
      pu.u[0] = __builtin_amdgcn_perm(fbits(e1), fbits(e0), 0x07060302);
      pu.u[1] = __builtin_amdgcn_perm(fbits(e3), fbits(e2), 0x07060302);
      oh[s][0] = pv_mfma(vf0, pu.v, oh[s][0]);
      oh[s][1] = pv_mfma(vf1, pu.v, oh[s][1]);
    }
  }

  // per-wave lsum: reduce over the 4 key-row groups (g)
  #pragma unroll
  for (int s = 0; s < 2; ++s) {
    lsum[s] += __shfl_xor(lsum[s], 16, 64);
    lsum[s] += __shfl_xor(lsum[s], 32, 64);
  }

  // publish per-wave lsum
  if (l < 16) {
    #pragma unroll
    for (int s = 0; s < 2; ++s) lf[wv * 32 + s * 16 + l] = lsum[s];
  }
  // round 1: waves 8-15 publish oh into slots 0-7
  if (wv >= 8) {
    float* slot = WS + (wv - 8) * 1024;
    #pragma unroll
    for (int s = 0; s < 2; ++s)
      #pragma unroll
      for (int hf = 0; hf < 2; ++hf)
        *(f32x4*)&slot[(s * 2 + hf) * 256 + l * 4] = oh[s][hf];
  }
  __syncthreads();
  // round 2: waves 0-7 accumulate; 4-7 republish. Wave 15 sums lsum partials.
  if (wv < 8) {
    float* slot = WS + wv * 1024;
    #pragma unroll
    for (int s = 0; s < 2; ++s)
      #pragma unroll
      for (int hf = 0; hf < 2; ++hf)
        oh[s][hf] += *(const f32x4*)&slot[(s * 2 + hf) * 256 + l * 4];
    if (wv >= 4) {
      #pragma unroll
      for (int s = 0; s < 2; ++s)
        #pragma unroll
        for (int hf = 0; hf < 2; ++hf)
          *(f32x4*)&slot[(s * 2 + hf) * 256 + l * 4] = oh[s][hf];
    }
  } else if (wv == 15 && l < 32) {
    float a = 0.f;
    #pragma unroll
    for (int ww = 0; ww < 16; ++ww) a += lf[ww * 32 + l];
    lfq[l] = a;
  }
  __syncthreads();
  // round 3: waves 0-3 accumulate slots 4-7, publish finals into slots 0-3
  if (wv < 4) {
    float* src = WS + (wv + 4) * 1024;
    float* dst = WS + wv * 1024;
    #pragma unroll
    for (int s = 0; s < 2; ++s)
      #pragma unroll
      for (int hf = 0; hf < 2; ++hf) {
        oh[s][hf] += *(const f32x4*)&src[(s * 2 + hf) * 256 + l * 4];
        *(f32x4*)&dst[(s * 2 + hf) * 256 + l * 4] = oh[s][hf];
      }
  }
  __syncthreads();

  // final: sum 4 slots, normalize, coalesced bf16 hi/lo out (1 elem/thread)
  {
    int q = t >> 5, d = t & 31;
    int s = q >> 4, cc = q & 15, hf = d >> 4, gg = (d & 15) >> 2, ii = d & 3;
    int off = (s * 2 + hf) * 256 + (gg * 16 + cc) * 4 + ii;
    float s4 = WS[off] + WS[1024 + off] + WS[2048 + off] + WS[3072 + off];
    float val = s4 / lfq[q];
    unsigned short hi = f2bf(val);
    float hfv = bfloat((unsigned)hi << 16);
    int idx = (nq + q) * 128 + h * 32 + d;
    Oth[idx] = hi;
    Otl[idx] = f2bf(val - hfv);
  }
}

// ---------- proj GEMM, split-bf16, W cast folded in-block ----------
__global__ __launch_bounds__(256)
void gemm_proj_kernel(const unsigned short* __restrict__ Oth,
                      const unsigned short* __restrict__ Otl,
                      const float* __restrict__ Wp, float* __restrict__ Y)
{
  const int t = threadIdx.x;
  const int w = t >> 6, c = t & 15, g = (t & 63) >> 4;
  const int n0 = blockIdx.x * 32;
  const int o_base = blockIdx.y * 64 + w * 16;
  f32x4 acc0 = {0.f, 0.f, 0.f, 0.f}, acc1 = {0.f, 0.f, 0.f, 0.f};
  #pragma unroll
  for (int ks = 0; ks < 4; ++ks) {
    const int ko = ks * 32 + g * 8;
    const float* wr = Wp + (o_base + c) * 128 + ko;
    union { unsigned u[4]; bf16x8 v; } ah, al;
    #pragma unroll
    for (int m = 0; m < 2; ++m) {
      f32x4 v = *(const f32x4*)&wr[m * 4];
      #pragma unroll
      for (int p = 0; p < 2; ++p) {
        unsigned hw = cvt_pk_bf16(v[2 * p], v[2 * p + 1]);
        float h0 = bfloat(hw << 16);
        float h1 = bfloat(hw & 0xFFFF0000u);
        ah.u[m * 2 + p] = hw;
        al.u[m * 2 + p] = cvt_pk_bf16(v[2 * p] - h0, v[2 * p + 1] - h1);
      }
    }
    bf16x8 bh0 = *(const bf16x8*)&Oth[(n0 + c) * 128 + ko];
    bf16x8 bl0 = *(const bf16x8*)&Otl[(n0 + c) * 128 + ko];
    bf16x8 bh1 = *(const bf16x8*)&Oth[(n0 + 16 + c) * 128 + ko];
    bf16x8 bl1 = *(const bf16x8*)&Otl[(n0 + 16 + c) * 128 + ko];
    acc0 = __builtin_amdgcn_mfma_f32_16x16x32_bf16(al.v, bh0, acc0, 0, 0, 0);
    acc0 = __builtin_amdgcn_mfma_f32_16x16x32_bf16(ah.v, bl0, acc0, 0, 0, 0);
    acc0 = __builtin_amdgcn_mfma_f32_16x16x32_bf16(ah.v, bh0, acc0, 0, 0, 0);
    acc1 = __builtin_amdgcn_mfma_f32_16x16x32_bf16(al.v, bh1, acc1, 0, 0, 0);
    acc1 = __builtin_amdgcn_mfma_f32_16x16x32_bf16(ah.v, bl1, acc1, 0, 0, 0);
    acc1 = __builtin_amdgcn_mfma_f32_16x16x32_bf16(ah.v, bh1, acc1, 0, 0, 0);
  }
  #pragma unroll
  for (int i = 0; i < 4; ++i) {
    Y[(o_base + 4 * g + i) * 4096 + n0 + c] = acc0[i];
    Y[(o_base + 4 * g + i) * 4096 + n0 + 16 + c] = acc1[i];
  }
}

extern "C" void kernel_launch(void* const* d_in, const int* in_sizes, int n_in,
                              void* d_out, int out_size, void* d_ws, size_t ws_size,
                              hipStream_t stream) {
  const float* xq    = (const float*)d_in[0];
  const float* xkv   = (const float*)d_in[1];
  const float* wqkv  = (const float*)d_in[2];
  const float* wdw   = (const float*)d_in[3];
  const float* wproj = (const float*)d_in[4];
  const float* temp  = (const float*)d_in[5];
  float* out = (float*)d_out;

  char* ws = (char*)d_ws;
  unsigned short* t16 = (unsigned short*)ws;                 // 3 MB  [384][4096]
  unsigned short* qt  = (unsigned short*)(ws + 3145728);     // 1 MB  [4][4096][32]
  unsigned short* kt  = (unsigned short*)(ws + 4194304);     // 1 MB
  unsigned short* vb  = (unsigned short*)(ws + 5242880);     // 1 MB  [128][4096]
  unsigned short* oth = (unsigned short*)(ws + 6291456);     // 1 MB  [4096][128]
  unsigned short* otl = (unsigned short*)(ws + 7340032);     // 1 MB

  qkvT_kernel<<<dim3(128, 6), 256, 0, stream>>>(xq, xkv, wqkv, t16);
  dwconv_kernel<<<dim3(1536), 256, 0, stream>>>(t16, wdw, temp, qt, kt, vb);
  attn_kernel<<<dim3(128, 4), 1024, 0, stream>>>(qt, kt, vb, oth, otl);
  gemm_proj_kernel<<<dim3(128, 2), 256, 0, stream>>>(oth, otl, wproj, out);
}

// Round 11
// 51.323 us; speedup vs baseline: 1.2885x; 1.2885x over previous
//
#include <hip/hip_runtime.h>

typedef short bf16x4 __attribute__((ext_vector_type(4)));
typedef short bf16x8 __attribute__((ext_vector_type(8)));
typedef float f32x4 __attribute__((ext_vector_type(4)));
typedef unsigned short u16x4 __attribute__((ext_vector_type(4)));
typedef unsigned short u16x8 __attribute__((ext_vector_type(8)));

__device__ __forceinline__ unsigned short f2bf(float f) {
  union { float f; unsigned u; } v; v.f = f;
  unsigned r = v.u + 0x7FFFu + ((v.u >> 16) & 1u);
  return (unsigned short)(r >> 16);
}
__device__ __forceinline__ unsigned fbits(float f) {
  union { float f; unsigned u; } x; x.f = f; return x.u;
}
__device__ __forceinline__ float bfloat(unsigned u) {
  union { unsigned u; float f; } x; x.u = u; return x.f;
}
__device__ __forceinline__ float fexp2(float x) {
#if __has_builtin(__builtin_amdgcn_exp2f)
  return __builtin_amdgcn_exp2f(x);
#else
  return exp2f(x);
#endif
}
// RNE packed f32->2xbf16 (verified on gfx950)
__device__ __forceinline__ unsigned cvt_pk_bf16(float a, float b) {
  unsigned r;
  asm("v_cvt_pk_bf16_f32 %0, %1, %2" : "=v"(r) : "v"(a), "v"(b));
  return r;
}
__device__ __forceinline__ f32x4 pv_mfma(bf16x4 a, bf16x4 b, f32x4 c) {
#if __has_builtin(__builtin_amdgcn_mfma_f32_16x16x16bf16_1k)
  return __builtin_amdgcn_mfma_f32_16x16x16bf16_1k(a, b, c, 0, 0, 0);
#else
  bf16x8 az = {a[0], a[1], a[2], a[3], 0, 0, 0, 0};
  bf16x8 bz = {b[0], b[1], b[2], b[3], 0, 0, 0, 0};
  return __builtin_amdgcn_mfma_f32_16x16x32_bf16(az, bz, c, 0, 0, 0);
#endif
}

// ---------- fused qkv: in-block X transpose+cast (LDS f32) + W cast + MFMA ----
__global__ __launch_bounds__(256)
void qkvT_kernel(const float* __restrict__ Xq, const float* __restrict__ Xkv,
                 const float* __restrict__ Wqkv, unsigned short* __restrict__ Y16)
{
  __shared__ float Xf[128][33];
  const int t = threadIdx.x;
  const int w = t >> 6, c = t & 15, g = (t & 63) >> 4;
  const int n0 = blockIdx.x * 32;
  const int ob = blockIdx.y;
  const float* X = (ob >= 2) ? Xkv : Xq;

  {
    const int kr = t >> 3;
    const int nc = (t & 7) * 4;
    #pragma unroll
    for (int pass = 0; pass < 4; ++pass) {
      int k = pass * 32 + kr;
      f32x4 v = *(const f32x4*)&X[k * 4096 + n0 + nc];
      Xf[k][nc + 0] = v[0];
      Xf[k][nc + 1] = v[1];
      Xf[k][nc + 2] = v[2];
      Xf[k][nc + 3] = v[3];
    }
  }

  union { unsigned u[4]; bf16x8 v; } af[4];
  {
    const float* wr = Wqkv + (ob * 64 + w * 16 + c) * 128;
    #pragma unroll
    for (int ks = 0; ks < 4; ++ks) {
      f32x4 v0 = *(const f32x4*)&wr[ks * 32 + g * 8];
      f32x4 v1 = *(const f32x4*)&wr[ks * 32 + g * 8 + 4];
      af[ks].u[0] = cvt_pk_bf16(v0[0], v0[1]);
      af[ks].u[1] = cvt_pk_bf16(v0[2], v0[3]);
      af[ks].u[2] = cvt_pk_bf16(v1[0], v1[1]);
      af[ks].u[3] = cvt_pk_bf16(v1[2], v1[3]);
    }
  }
  __syncthreads();

  union { unsigned u[4]; bf16x8 v; } bfr[2][4];
  #pragma unroll
  for (int s = 0; s < 2; ++s) {
    const int n = s * 16 + c;
    #pragma unroll
    for (int ks = 0; ks < 4; ++ks) {
      const int kb = ks * 32 + g * 8;
      #pragma unroll
      for (int m = 0; m < 4; ++m)
        bfr[s][ks].u[m] = cvt_pk_bf16(Xf[kb + 2 * m][n], Xf[kb + 2 * m + 1][n]);
    }
  }

  f32x4 acc[2] = {{0.f, 0.f, 0.f, 0.f}, {0.f, 0.f, 0.f, 0.f}};
  #pragma unroll
  for (int ks = 0; ks < 4; ++ks) {
    acc[0] = __builtin_amdgcn_mfma_f32_16x16x32_bf16(af[ks].v, bfr[0][ks].v, acc[0], 0, 0, 0);
    acc[1] = __builtin_amdgcn_mfma_f32_16x16x32_bf16(af[ks].v, bfr[1][ks].v, acc[1], 0, 0, 0);
  }
  #pragma unroll
  for (int s = 0; s < 2; ++s)
    #pragma unroll
    for (int i = 0; i < 4; ++i)
      Y16[(ob * 64 + w * 16 + 4 * g + i) * 4096 + n0 + s * 16 + c] = f2bf(acc[s][i]);
}

// ---------- depthwise 3x3 SAME, quarter-plane blocks ----------
__global__ __launch_bounds__(256)
void dwconv_kernel(const unsigned short* __restrict__ T16, const float* __restrict__ Wd,
                   const float* __restrict__ temp, unsigned short* __restrict__ Qt,
                   unsigned short* __restrict__ Kt, unsigned short* __restrict__ Vb)
{
  __shared__ float P[18 * 64];
  const int jc = blockIdx.x >> 2;
  const int qtr = blockIdx.x & 3;
  const int y0 = qtr * 16;
  const int t = threadIdx.x;
  const unsigned short* in = T16 + jc * 4096;
  #pragma unroll
  for (int i = 0; i < 5; ++i) {
    int idx = i * 256 + t;
    if (idx < 1152) {
      int row = idx >> 6, col = idx & 63;
      int sy = y0 - 1 + row;
      P[idx] = (sy >= 0 && sy < 64) ? bfloat((unsigned)in[sy * 64 + col] << 16) : 0.f;
    }
  }
  float w[9];
  #pragma unroll
  for (int k = 0; k < 9; ++k) w[k] = Wd[jc * 9 + k];
  const float scale = (jc < 128) ? temp[jc >> 5] * 1.4426950408889634f : 1.0f;
  __syncthreads();

  const int hh = (jc >> 5) & 3, dd = jc & 31;
  unsigned short* outT = (jc < 128 ? Qt : Kt) + hh * 4096 * 32 + dd;
  unsigned short* outV = Vb + (jc - 256) * 4096 + y0 * 64;
  const bool is_v = (jc >= 256);

  #pragma unroll
  for (int i = 0; i < 4; ++i) {
    int p = i * 256 + t;
    int yl = p >> 6, x = p & 63;
    float acc = 0.f;
    #pragma unroll
    for (int dy = 0; dy < 3; ++dy) {
      int base = (yl + dy) * 64 + x;
      if (x > 0)  acc += w[dy * 3 + 0] * P[base - 1];
      acc += w[dy * 3 + 1] * P[base];
      if (x < 63) acc += w[dy * 3 + 2] * P[base + 1];
    }
    unsigned short r = f2bf(acc * scale);
    if (is_v) outV[p] = r;
    else      outT[(y0 * 64 + p) * 32] = r;
  }
}

// ----------------------- flash attention (bf16 MFMA) -----------------------
// R9 shape (64q/wave, grid (64,4), lb(1024,4) -> 128-reg cap), with the j-loop
// hand-pipelined at depth 2: named double-buffer regs force the allocator to
// keep 2 iterations of K/V loads in flight across the compute (ILP fix for the
// VMEM-latency stall measured in R10: VGPR=32 -> zero prefetch -> 43us).
__global__ __launch_bounds__(1024, 4)
void attn_kernel(const unsigned short* __restrict__ Qt,
                 const unsigned short* __restrict__ Kt,
                 const unsigned short* __restrict__ Vb,
                 unsigned short* __restrict__ Oth, unsigned short* __restrict__ Otl)
{
  extern __shared__ __align__(16) char lds[];
  float* WS = (float*)lds;                 // 8 slots x 2048 f32 (64 KB)
  float* lf = (float*)(lds + 65536);       // [16][64] per-wave lsum (4 KB)
  const int t = threadIdx.x;
  const int wv = t >> 6;
  const int l = t & 63;
  const int c = l & 15, g = l >> 4;
  const int h = blockIdx.y;
  const int nq = blockIdx.x * 64;
  const int m0w = wv * 256;

  bf16x8 qf[4];
  #pragma unroll
  for (int s = 0; s < 4; ++s)
    qf[s] = *(const bf16x8*)&Qt[(h * 4096 + nq + s * 16 + c) * 32 + g * 8];

  f32x4 oh[4][2];
  #pragma unroll
  for (int s = 0; s < 4; ++s) {
    oh[s][0] = (f32x4){0.f, 0.f, 0.f, 0.f};
    oh[s][1] = (f32x4){0.f, 0.f, 0.f, 0.f};
  }
  float lsum[4] = {0.f, 0.f, 0.f, 0.f};

  const unsigned short* Kb  = Kt + (h * 4096 + m0w + c) * 32 + g * 8;
  const unsigned short* Vb0 = Vb + (h * 32 + c) * 4096 + m0w + g * 4;
  const unsigned short* Vb1 = Vb0 + 16 * 4096;

  auto compute = [&](bf16x8 kf, bf16x4 vf0, bf16x4 vf1) {
    #pragma unroll
    for (int s = 0; s < 4; ++s) {
      f32x4 z = {0.f, 0.f, 0.f, 0.f};
      f32x4 sv = __builtin_amdgcn_mfma_f32_16x16x32_bf16(kf, qf[s], z, 0, 0, 0);
      float e0 = fexp2(sv[0]);
      float e1 = fexp2(sv[1]);
      float e2 = fexp2(sv[2]);
      float e3 = fexp2(sv[3]);
      lsum[s] += (e0 + e1) + (e2 + e3);
      union { unsigned u[2]; bf16x4 v; } pu;
      pu.u[0] = __builtin_amdgcn_perm(fbits(e1), fbits(e0), 0x07060302);
      pu.u[1] = __builtin_amdgcn_perm(fbits(e3), fbits(e2), 0x07060302);
      oh[s][0] = pv_mfma(vf0, pu.v, oh[s][0]);
      oh[s][1] = pv_mfma(vf1, pu.v, oh[s][1]);
    }
  };

  // depth-2 software pipeline over the 16 key-chunks
  bf16x8 k0 = *(const bf16x8*)&Kb[0 * 512];
  bf16x8 k1 = *(const bf16x8*)&Kb[1 * 512];
  bf16x4 a0 = *(const bf16x4*)&Vb0[0 * 16];
  bf16x4 b0 = *(const bf16x4*)&Vb1[0 * 16];
  bf16x4 a1 = *(const bf16x4*)&Vb0[1 * 16];
  bf16x4 b1 = *(const bf16x4*)&Vb1[1 * 16];
  #pragma unroll 1
  for (int j = 0; j < 14; j += 2) {
    bf16x8 kc = k0; bf16x4 ac = a0, bc = b0;
    k0 = *(const bf16x8*)&Kb[(j + 2) * 512];
    a0 = *(const bf16x4*)&Vb0[(j + 2) * 16];
    b0 = *(const bf16x4*)&Vb1[(j + 2) * 16];
    compute(kc, ac, bc);
    kc = k1; ac = a1; bc = b1;
    k1 = *(const bf16x8*)&Kb[(j + 3) * 512];
    a1 = *(const bf16x4*)&Vb0[(j + 3) * 16];
    b1 = *(const bf16x4*)&Vb1[(j + 3) * 16];
    compute(kc, ac, bc);
  }
  compute(k0, a0, b0);
  compute(k1, a1, b1);

  // all 64 lanes hold the full wave lsum per query s*16+c after this
  #pragma unroll
  for (int s = 0; s < 4; ++s) {
    lsum[s] += __shfl_xor(lsum[s], 16, 64);
    lsum[s] += __shfl_xor(lsum[s], 32, 64);
  }

  // publish per-wave lsum once
  if (l < 16) {
    #pragma unroll
    for (int s = 0; s < 4; ++s) lf[wv * 64 + s * 16 + l] = lsum[s];
  }
  // round 1: waves 8-15 publish oh into slots 0-7
  if (wv >= 8) {
    float* slot = WS + (wv - 8) * 2048;
    #pragma unroll
    for (int s = 0; s < 4; ++s)
      #pragma unroll
      for (int hf = 0; hf < 2; ++hf)
        *(f32x4*)&slot[(s * 2 + hf) * 256 + l * 4] = oh[s][hf];
  }
  __syncthreads();
  // waves 0-7 accumulate; waves 4-7 republish their updated partials
  if (wv < 8) {
    float* slot = WS + wv * 2048;
    #pragma unroll
    for (int s = 0; s < 4; ++s)
      #pragma unroll
      for (int hf = 0; hf < 2; ++hf)
        oh[s][hf] += *(const f32x4*)&slot[(s * 2 + hf) * 256 + l * 4];
    if (wv >= 4) {
      #pragma unroll
      for (int s = 0; s < 4; ++s)
        #pragma unroll
        for (int hf = 0; hf < 2; ++hf)
          *(f32x4*)&slot[(s * 2 + hf) * 256 + l * 4] = oh[s][hf];
    }
  }
  __syncthreads();
  // waves 0-3 accumulate slots 4-7, publish finals into slots 0-3
  if (wv < 4) {
    float* src = WS + (wv + 4) * 2048;
    float* dst = WS + wv * 2048;
    #pragma unroll
    for (int s = 0; s < 4; ++s)
      #pragma unroll
      for (int hf = 0; hf < 2; ++hf) {
        oh[s][hf] += *(const f32x4*)&src[(s * 2 + hf) * 256 + l * 4];
        *(f32x4*)&dst[(s * 2 + hf) * 256 + l * 4] = oh[s][hf];
      }
  }
  __syncthreads();

  // final: sum 4 slots + 16 lsum partials, normalize, coalesced bf16 hi/lo out
  #pragma unroll
  for (int e = t; e < 2048; e += 1024) {
    int q = e >> 5, d = e & 31;
    int s = q >> 4, cc = q & 15, hf = d >> 4, gg = (d & 15) >> 2, ii = d & 3;
    int off = (s * 2 + hf) * 256 + (gg * 16 + cc) * 4 + ii;
    float s4 = WS[off] + WS[2048 + off] + WS[4096 + off] + WS[6144 + off];
    float li = 0.f;
    #pragma unroll
    for (int ww = 0; ww < 16; ++ww) li += lf[ww * 64 + q];
    float val = s4 / li;
    unsigned short hi = f2bf(val);
    float hfv = bfloat((unsigned)hi << 16);
    int idx = (nq + q) * 128 + h * 32 + d;
    Oth[idx] = hi;
    Otl[idx] = f2bf(val - hfv);
  }
}

// ---------- proj GEMM, split-bf16, W cast folded in-block ----------
__global__ __launch_bounds__(256)
void gemm_proj_kernel(const unsigned short* __restrict__ Oth,
                      const unsigned short* __restrict__ Otl,
                      const float* __restrict__ Wp, float* __restrict__ Y)
{
  const int t = threadIdx.x;
  const int w = t >> 6, c = t & 15, g = (t & 63) >> 4;
  const int n0 = blockIdx.x * 32;
  const int o_base = blockIdx.y * 64 + w * 16;
  f32x4 acc0 = {0.f, 0.f, 0.f, 0.f}, acc1 = {0.f, 0.f, 0.f, 0.f};
  #pragma unroll
  for (int ks = 0; ks < 4; ++ks) {
    const int ko = ks * 32 + g * 8;
    const float* wr = Wp + (o_base + c) * 128 + ko;
    union { unsigned u[4]; bf16x8 v; } ah, al;
    #pragma unroll
    for (int m = 0; m < 2; ++m) {
      f32x4 v = *(const f32x4*)&wr[m * 4];
      #pragma unroll
      for (int p = 0; p < 2; ++p) {
        unsigned hw = cvt_pk_bf16(v[2 * p], v[2 * p + 1]);
        float h0 = bfloat(hw << 16);
        float h1 = bfloat(hw & 0xFFFF0000u);
        ah.u[m * 2 + p] = hw;
        al.u[m * 2 + p] = cvt_pk_bf16(v[2 * p] - h0, v[2 * p + 1] - h1);
      }
    }
    bf16x8 bh0 = *(const bf16x8*)&Oth[(n0 + c) * 128 + ko];
    bf16x8 bl0 = *(const bf16x8*)&Otl[(n0 + c) * 128 + ko];
    bf16x8 bh1 = *(const bf16x8*)&Oth[(n0 + 16 + c) * 128 + ko];
    bf16x8 bl1 = *(const bf16x8*)&Otl[(n0 + 16 + c) * 128 + ko];
    acc0 = __builtin_amdgcn_mfma_f32_16x16x32_bf16(al.v, bh0, acc0, 0, 0, 0);
    acc0 = __builtin_amdgcn_mfma_f32_16x16x32_bf16(ah.v, bl0, acc0, 0, 0, 0);
    acc0 = __builtin_amdgcn_mfma_f32_16x16x32_bf16(ah.v, bh0, acc0, 0, 0, 0);
    acc1 = __builtin_amdgcn_mfma_f32_16x16x32_bf16(al.v, bh1, acc1, 0, 0, 0);
    acc1 = __builtin_amdgcn_mfma_f32_16x16x32_bf16(ah.v, bl1, acc1, 0, 0, 0);
    acc1 = __builtin_amdgcn_mfma_f32_16x16x32_bf16(ah.v, bh1, acc1, 0, 0, 0);
  }
  #pragma unroll
  for (int i = 0; i < 4; ++i) {
    Y[(o_base + 4 * g + i) * 4096 + n0 + c] = acc0[i];
    Y[(o_base + 4 * g + i) * 4096 + n0 + 16 + c] = acc1[i];
  }
}

extern "C" void kernel_launch(void* const* d_in, const int* in_sizes, int n_in,
                              void* d_out, int out_size, void* d_ws, size_t ws_size,
                              hipStream_t stream) {
  const float* xq    = (const float*)d_in[0];
  const float* xkv   = (const float*)d_in[1];
  const float* wqkv  = (const float*)d_in[2];
  const float* wdw   = (const float*)d_in[3];
  const float* wproj = (const float*)d_in[4];
  const float* temp  = (const float*)d_in[5];
  float* out = (float*)d_out;

  char* ws = (char*)d_ws;
  unsigned short* t16 = (unsigned short*)ws;                 // 3 MB  [384][4096]
  unsigned short* qt  = (unsigned short*)(ws + 3145728);     // 1 MB  [4][4096][32]
  unsigned short* kt  = (unsigned short*)(ws + 4194304);     // 1 MB
  unsigned short* vb  = (unsigned short*)(ws + 5242880);     // 1 MB  [128][4096]
  unsigned short* oth = (unsigned short*)(ws + 6291456);     // 1 MB  [4096][128]
  unsigned short* otl = (unsigned short*)(ws + 7340032);     // 1 MB

  qkvT_kernel<<<dim3(128, 6), 256, 0, stream>>>(xq, xkv, wqkv, t16);
  dwconv_kernel<<<dim3(1536), 256, 0, stream>>>(t16, wdw, temp, qt, kt, vb);
  attn_kernel<<<dim3(64, 4), 1024, 69632, stream>>>(qt, kt, vb, oth, otl);
  gemm_proj_kernel<<<dim3(128, 2), 256, 0, stream>>>(oth, otl, wproj, out);
}